// Round 5
// baseline (4728.689 us; speedup 1.0000x reference)
//
#include <hip/hip_runtime.h>
#include <hip/hip_bf16.h>

#define H 128
#define NN 50000
#define NE 500000
#define NB 64
#define NSTEPS 3
#define LROW 136  // 128 + 8 pad

// Wave-local LDS ordering: waves use disjoint LDS slices, DS pipe is in-order
// per wave; we only need HW drain + a compiler reorder barrier. Cheaper than
// s_barrier (no wave rendezvous, vmcnt loads stay in flight).
#define LDS_FENCE() asm volatile("s_waitcnt lgkmcnt(0)" ::: "memory")

typedef __bf16 bf16x8 __attribute__((ext_vector_type(8)));
typedef float f32x4 __attribute__((ext_vector_type(4)));

__device__ __forceinline__ f32x4 mfma16(bf16x8 a, bf16x8 b, f32x4 c) {
  return __builtin_amdgcn_mfma_f32_16x16x32_bf16(a, b, c, 0, 0, 0);
}
__device__ __forceinline__ float sigm(float x) { return 1.f / (1.f + __expf(-x)); }
__device__ __forceinline__ float tanh_(float x) { return 1.f - 2.f / (1.f + __expf(2.f * x)); }
__device__ __forceinline__ bf16x8 cvt8s(float4 lo, float4 hi, float s) {
  bf16x8 v;
  v[0] = (__bf16)(lo.x * s); v[1] = (__bf16)(lo.y * s);
  v[2] = (__bf16)(lo.z * s); v[3] = (__bf16)(lo.w * s);
  v[4] = (__bf16)(hi.x * s); v[5] = (__bf16)(hi.y * s);
  v[6] = (__bf16)(hi.z * s); v[7] = (__bf16)(hi.w * s);
  return v;
}
__device__ __forceinline__ bf16x8 g8(const __bf16* p) { return *reinterpret_cast<const bf16x8*>(p); }
__device__ __forceinline__ bf16x8 g8(const float* p) {
  float4 lo = *(const float4*)p, hi = *(const float4*)(p + 4);
  return cvt8s(lo, hi, 1.f);
}
__device__ __forceinline__ bf16x8 zero8() {
  bf16x8 v;
#pragma unroll
  for (int i = 0; i < 8; ++i) v[i] = (__bf16)0.f;
  return v;
}

// ---------------- staged weight layout (elements, bf16) ----------------
#define OW_EW1 0        // 512*128
#define OW_EW2 65536    // 128*128
#define OW_NW1 81920    // 384*128
#define OW_NW2 131072   // 128*128
#define OW_GW1 147456   // 256*128
#define OW_GW2 180224   // 128*128
#define OW_EG  196608   // packed GRU pair: 128*16*6*8 = 98304
#define OW_NG  294912
#define OW_GG  393216
#define OW_TOTAL 491520

struct W6 { const float* p[6]; };
struct G6 { const float* p[6]; };  // eih, ehh, nih, nhh, gih, ghh

__global__ __launch_bounds__(256) void cvt_kernel(W6 w, __bf16* __restrict__ out) {
  const int off[7] = {OW_EW1, OW_EW2, OW_NW1, OW_NW2, OW_GW1, OW_GW2, OW_EG};
  int e = (blockIdx.x * 256 + threadIdx.x) * 8;
  if (e >= OW_EG) return;
  int s = 0;
#pragma unroll
  for (int i = 1; i < 6; ++i)
    if (e >= off[i]) s = i;
  const float* src = w.p[s] + (e - off[s]);
  float4 lo = *(const float4*)src, hi = *(const float4*)(src + 4);
  *reinterpret_cast<bf16x8*>(out + e) = cvt8s(lo, hi, 1.f);
}

// pack wih/whh pairs: dst[((row*16 + kq)*6 + g)*8 + j]  (g: 0..2=ih r/z/g, 3..5=hh r/z/g)
__global__ __launch_bounds__(256) void gru_pack_kernel(G6 g, __bf16* __restrict__ out) {
  int t = blockIdx.x * 256 + threadIdx.x;
  if (t >= 3 * 12288) return;
  int pair = t / 12288, rem = t - pair * 12288;
  int gg = rem % 6, rk = rem / 6;
  int row = rk >> 4, kq = rk & 15;
  const float* src = g.p[pair * 2 + (gg >= 3 ? 1 : 0)] +
                     ((size_t)((gg % 3) * 128 + row)) * 128 + kq * 8;
  float4 lo = *(const float4*)src, hi = *(const float4*)(src + 4);
  *reinterpret_cast<bf16x8*>(out + (size_t)pair * 98304 + (size_t)rem * 8) = cvt8s(lo, hi, 1.f);
}

__global__ void count_kernel(const int* __restrict__ dst, const int* __restrict__ batch,
                             int* __restrict__ dcnt, int* __restrict__ ncnt) {
  int i = blockIdx.x * 256 + threadIdx.x;
  if (i < NE) atomicAdd(&dcnt[dst[i]], 1);
  if (i < NN) atomicAdd(&ncnt[batch[i]], 1);
}

// identity B-fragments: C[m][col] = A[m][16*sel + col]
__device__ __forceinline__ void make_id(bf16x8& id0, bf16x8& id1, int lm, int quad) {
  id0 = zero8(); id1 = zero8();
#pragma unroll
  for (int jj = 0; jj < 8; ++jj) {
    if ((quad == (lm >> 3)) && (jj == (lm & 7))) id0[jj] = (__bf16)1.f;
    if ((quad == 2 + (lm >> 3)) && (jj == (lm & 7))) id1[jj] = (__bf16)1.f;
  }
}

// ---------------- edge model: MLP(4H->H->H) + GRU, per-wave M=32 ----------------
template <typename WT, bool PK>
__global__ __launch_bounds__(256, 2) void edge_kernel(
    const float* __restrict__ x, const int* __restrict__ ei,
    float* __restrict__ ea, const float* __restrict__ u, const int* __restrict__ batch,
    const WT* __restrict__ w1, const float* __restrict__ b1,
    const WT* __restrict__ w2, const float* __restrict__ b2,
    const WT* __restrict__ gw, const WT* __restrict__ wihf, const WT* __restrict__ whhf,
    const float* __restrict__ bih, const float* __restrict__ bhh,
    float* __restrict__ agg, int ws_ok) {
  __shared__ __bf16 lds[4][32 * LROW];
  const int* src = ei;
  const int* dst = ei + NE;
  const int wave = threadIdx.x >> 6, lane = threadIdx.x & 63;
  const int lm = lane & 15, quad = lane >> 4;
  const long base = ((long)blockIdx.x * 4 + wave) * 32;
  __bf16* myl = lds[wave];

  long tA0 = base + lm;      const int eA0 = (int)(tA0 < NE ? tA0 : NE - 1);
  long tA1 = base + 16 + lm; const int eA1 = (int)(tA1 < NE ? tA1 : NE - 1);
  const int s0 = src[eA0], s1 = src[eA1];
  const int d0 = dst[eA0], d1 = dst[eA1];
  const int g0 = batch[s0], g1 = batch[s1];

  // ---- layer 1: K = 512 over 4 gathered segments ----
  const float* pp0[4] = {x + (size_t)s0 * H, x + (size_t)d0 * H, ea + (size_t)eA0 * H, u + (size_t)g0 * H};
  const float* pp1[4] = {x + (size_t)s1 * H, x + (size_t)d1 * H, ea + (size_t)eA1 * H, u + (size_t)g1 * H};
  f32x4 acc[8][2] = {};
  bf16x8 ah0[4], ah1[4];  // edge_attr A-frags (GRU h-path + identity-hold)
#pragma unroll
  for (int seg = 0; seg < 4; ++seg) {
#pragma unroll
    for (int ss = 0; ss < 4; ++ss) {
      const int kk = ss * 32 + quad * 8;
      bf16x8 a0 = g8(pp0[seg] + kk), a1 = g8(pp1[seg] + kk);
      if (seg == 2) { ah0[ss] = a0; ah1[ss] = a1; }
#pragma unroll
      for (int n = 0; n < 8; ++n) {
        bf16x8 bf = g8(w1 + (size_t)(n * 16 + lm) * 512 + seg * 128 + kk);
        acc[n][0] = mfma16(a0, bf, acc[n][0]);
        acc[n][1] = mfma16(a1, bf, acc[n][1]);
      }
    }
  }
#pragma unroll
  for (int n = 0; n < 8; ++n) {
    const float bb = b1[n * 16 + lm];
#pragma unroll
    for (int sub = 0; sub < 2; ++sub)
#pragma unroll
      for (int r = 0; r < 4; ++r) {
        float v = fmaxf(acc[n][sub][r] + bb, 0.f);
        myl[(sub * 16 + quad * 4 + r) * LROW + n * 16 + lm] = (__bf16)v;
      }
  }
  LDS_FENCE();
  // ---- layer 2 ----
  bf16x8 a20[4], a21[4];
#pragma unroll
  for (int ss = 0; ss < 4; ++ss) {
    a20[ss] = g8(myl + lm * LROW + ss * 32 + quad * 8);
    a21[ss] = g8(myl + (16 + lm) * LROW + ss * 32 + quad * 8);
  }
  f32x4 acc2[8][2] = {};
#pragma unroll
  for (int ss = 0; ss < 4; ++ss) {
    const int kk = ss * 32 + quad * 8;
#pragma unroll
    for (int n = 0; n < 8; ++n) {
      bf16x8 bf = g8(w2 + (size_t)(n * 16 + lm) * H + kk);
      acc2[n][0] = mfma16(a20[ss], bf, acc2[n][0]);
      acc2[n][1] = mfma16(a21[ss], bf, acc2[n][1]);
    }
  }
  LDS_FENCE();
#pragma unroll
  for (int n = 0; n < 8; ++n) {
    const float bb = b2[n * 16 + lm];
#pragma unroll
    for (int sub = 0; sub < 2; ++sub)
#pragma unroll
      for (int r = 0; r < 4; ++r)
        myl[(sub * 16 + quad * 4 + r) * LROW + n * 16 + lm] = (__bf16)(acc2[n][sub][r] + bb);
  }
  LDS_FENCE();
  // ---- GRU ----
  bf16x8 ao0[4], ao1[4];
#pragma unroll
  for (int ss = 0; ss < 4; ++ss) {
    ao0[ss] = g8(myl + lm * LROW + ss * 32 + quad * 8);
    ao1[ss] = g8(myl + (16 + lm) * LROW + ss * 32 + quad * 8);
  }
  bf16x8 id0, id1;
  make_id(id0, id1, lm, quad);
  int erow[2][4], drow[2][4];
#pragma unroll
  for (int sub = 0; sub < 2; ++sub)
#pragma unroll
    for (int r = 0; r < 4; ++r) {
      long e = base + sub * 16 + quad * 4 + r;
      int ec = (int)(e < NE ? e : NE - 1);
      erow[sub][r] = ec;
      drow[sub][r] = dst[ec];
    }
  const f32x4 fz = {0.f, 0.f, 0.f, 0.f};
#pragma unroll 2
  for (int n = 0; n < 8; ++n) {
    // pass A: r,z gates
    f32x4 arr[2] = {}, azz[2] = {}, hrr[2] = {}, hzz[2] = {};
#pragma unroll
    for (int ss = 0; ss < 4; ++ss) {
      bf16x8 wr, wz, vr, vz;
      if constexpr (PK) {
        const WT* gb = gw + (size_t)(((n * 16 + lm) * 16 + ss * 4 + quad) * 48);
        wr = g8(gb); wz = g8(gb + 8); vr = g8(gb + 24); vz = g8(gb + 32);
      } else {
        const int wr0 = (n * 16 + lm) * H, kk = ss * 32 + quad * 8;
        wr = g8(wihf + wr0 + kk); wz = g8(wihf + wr0 + 128 * H + kk);
        vr = g8(whhf + wr0 + kk); vz = g8(whhf + wr0 + 128 * H + kk);
      }
      arr[0] = mfma16(ao0[ss], wr, arr[0]); arr[1] = mfma16(ao1[ss], wr, arr[1]);
      azz[0] = mfma16(ao0[ss], wz, azz[0]); azz[1] = mfma16(ao1[ss], wz, azz[1]);
      hrr[0] = mfma16(ah0[ss], vr, hrr[0]); hrr[1] = mfma16(ah1[ss], vr, hrr[1]);
      hzz[0] = mfma16(ah0[ss], vz, hzz[0]); hzz[1] = mfma16(ah1[ss], vz, hzz[1]);
    }
    const int c = n * 16 + lm;
    const float bir = bih[c], biz = bih[c + 128];
    const float bhr = bhh[c], bhz = bhh[c + 128];
    float rg[2][4], zg[2][4];
#pragma unroll
    for (int sub = 0; sub < 2; ++sub)
#pragma unroll
      for (int r = 0; r < 4; ++r) {
        rg[sub][r] = sigm(arr[sub][r] + bir + hrr[sub][r] + bhr);
        zg[sub][r] = sigm(azz[sub][r] + biz + hzz[sub][r] + bhz);
      }
    // pass B: g gate
    f32x4 agi[2] = {}, agh[2] = {};
#pragma unroll
    for (int ss = 0; ss < 4; ++ss) {
      bf16x8 wg, vg;
      if constexpr (PK) {
        const WT* gb = gw + (size_t)(((n * 16 + lm) * 16 + ss * 4 + quad) * 48);
        wg = g8(gb + 16); vg = g8(gb + 40);
      } else {
        const int wr0 = (n * 16 + lm) * H, kk = ss * 32 + quad * 8;
        wg = g8(wihf + wr0 + 256 * H + kk); vg = g8(whhf + wr0 + 256 * H + kk);
      }
      agi[0] = mfma16(ao0[ss], wg, agi[0]); agi[1] = mfma16(ao1[ss], wg, agi[1]);
      agh[0] = mfma16(ah0[ss], vg, agh[0]); agh[1] = mfma16(ah1[ss], vg, agh[1]);
    }
    // hold = old edge_attr in C-layout via identity MFMA (no global re-read)
    bf16x8 idn = (n & 1) ? id1 : id0;
    f32x4 hold0 = mfma16(ah0[n >> 1], idn, fz);
    f32x4 hold1 = mfma16(ah1[n >> 1], idn, fz);
    const float big = bih[c + 256], bhg = bhh[c + 256];
#pragma unroll
    for (int sub = 0; sub < 2; ++sub)
#pragma unroll
      for (int r = 0; r < 4; ++r) {
        float ng = tanh_(agi[sub][r] + big + rg[sub][r] * (agh[sub][r] + bhg));
        float hold = sub ? hold1[r] : hold0[r];
        float hnew = (1.f - zg[sub][r]) * ng + zg[sub][r] * hold;
        int e = erow[sub][r];
        if (base + sub * 16 + quad * 4 + r < NE) {
          ea[(size_t)e * H + c] = hnew;
          if (ws_ok) atomicAdd(&agg[drow[sub][r] * H + c], hnew);
        }
      }
  }
}

// ---------------- node model: MLP(3H->H->H) + GRU, per-wave M=16 ----------------
template <typename WT, bool PK>
__global__ __launch_bounds__(256, 3) void node_kernel(
    float* __restrict__ x, const float* __restrict__ u, const int* __restrict__ batch,
    const float* __restrict__ agg, const int* __restrict__ dcnt,
    const WT* __restrict__ w1, const float* __restrict__ b1,
    const WT* __restrict__ w2, const float* __restrict__ b2,
    const WT* __restrict__ gw, const WT* __restrict__ wihf, const WT* __restrict__ whhf,
    const float* __restrict__ bih, const float* __restrict__ bhh,
    float* __restrict__ xsum, int ws_ok) {
  __shared__ __bf16 lds[4][16 * LROW];
  const int wave = threadIdx.x >> 6, lane = threadIdx.x & 63;
  const int lm = lane & 15, quad = lane >> 4;
  const long base = ((long)blockIdx.x * 4 + wave) * 16;
  __bf16* myl = lds[wave];

  long tA0 = base + lm;
  const int iA0 = (int)(tA0 < NN ? tA0 : NN - 1);
  const int g0 = batch[iA0];
  const float inv0 = ws_ok ? 1.f / (float)max(dcnt[iA0], 1) : 1.f;

  f32x4 acc[8] = {};
  bf16x8 ah0[4];
#pragma unroll
  for (int seg = 0; seg < 3; ++seg) {
#pragma unroll
    for (int ss = 0; ss < 4; ++ss) {
      const int kk = ss * 32 + quad * 8;
      bf16x8 a0;
      if (seg == 0) {
        a0 = g8(x + (size_t)iA0 * H + kk);
        ah0[ss] = a0;
      } else if (seg == 1) {
        if (ws_ok) {
          float4 lo = *(const float4*)(agg + (size_t)iA0 * H + kk);
          float4 hi = *(const float4*)(agg + (size_t)iA0 * H + kk + 4);
          a0 = cvt8s(lo, hi, inv0);
        } else a0 = zero8();
      } else {
        a0 = g8(u + (size_t)g0 * H + kk);
      }
#pragma unroll
      for (int n = 0; n < 8; ++n) {
        bf16x8 bf = g8(w1 + (size_t)(n * 16 + lm) * 384 + seg * 128 + kk);
        acc[n] = mfma16(a0, bf, acc[n]);
      }
    }
  }
#pragma unroll
  for (int n = 0; n < 8; ++n) {
    const float bb = b1[n * 16 + lm];
#pragma unroll
    for (int r = 0; r < 4; ++r)
      myl[(quad * 4 + r) * LROW + n * 16 + lm] = (__bf16)fmaxf(acc[n][r] + bb, 0.f);
  }
  LDS_FENCE();
  bf16x8 a20[4];
#pragma unroll
  for (int ss = 0; ss < 4; ++ss) a20[ss] = g8(myl + lm * LROW + ss * 32 + quad * 8);
  f32x4 acc2[8] = {};
#pragma unroll
  for (int ss = 0; ss < 4; ++ss) {
    const int kk = ss * 32 + quad * 8;
#pragma unroll
    for (int n = 0; n < 8; ++n) {
      bf16x8 bf = g8(w2 + (size_t)(n * 16 + lm) * H + kk);
      acc2[n] = mfma16(a20[ss], bf, acc2[n]);
    }
  }
  LDS_FENCE();
#pragma unroll
  for (int n = 0; n < 8; ++n) {
    const float bb = b2[n * 16 + lm];
#pragma unroll
    for (int r = 0; r < 4; ++r)
      myl[(quad * 4 + r) * LROW + n * 16 + lm] = (__bf16)(acc2[n][r] + bb);
  }
  LDS_FENCE();
  bf16x8 ao0[4];
#pragma unroll
  for (int ss = 0; ss < 4; ++ss) ao0[ss] = g8(myl + lm * LROW + ss * 32 + quad * 8);
  bf16x8 id0, id1;
  make_id(id0, id1, lm, quad);
  int irow[4], brow[4];
#pragma unroll
  for (int r = 0; r < 4; ++r) {
    long i = base + quad * 4 + r;
    int ic = (int)(i < NN ? i : NN - 1);
    irow[r] = ic;
    brow[r] = batch[ic];
  }
  const f32x4 fz = {0.f, 0.f, 0.f, 0.f};
#pragma unroll 2
  for (int n = 0; n < 8; ++n) {
    f32x4 arr = {}, azz = {}, hrr = {}, hzz = {};
#pragma unroll
    for (int ss = 0; ss < 4; ++ss) {
      bf16x8 wr, wz, vr, vz;
      if constexpr (PK) {
        const WT* gb = gw + (size_t)(((n * 16 + lm) * 16 + ss * 4 + quad) * 48);
        wr = g8(gb); wz = g8(gb + 8); vr = g8(gb + 24); vz = g8(gb + 32);
      } else {
        const int wr0 = (n * 16 + lm) * H, kk = ss * 32 + quad * 8;
        wr = g8(wihf + wr0 + kk); wz = g8(wihf + wr0 + 128 * H + kk);
        vr = g8(whhf + wr0 + kk); vz = g8(whhf + wr0 + 128 * H + kk);
      }
      arr = mfma16(ao0[ss], wr, arr);
      azz = mfma16(ao0[ss], wz, azz);
      hrr = mfma16(ah0[ss], vr, hrr);
      hzz = mfma16(ah0[ss], vz, hzz);
    }
    const int c = n * 16 + lm;
    const float bir = bih[c], biz = bih[c + 128];
    const float bhr = bhh[c], bhz = bhh[c + 128];
    float rg[4], zg[4];
#pragma unroll
    for (int r = 0; r < 4; ++r) {
      rg[r] = sigm(arr[r] + bir + hrr[r] + bhr);
      zg[r] = sigm(azz[r] + biz + hzz[r] + bhz);
    }
    f32x4 agi = {}, agh = {};
#pragma unroll
    for (int ss = 0; ss < 4; ++ss) {
      bf16x8 wg, vg;
      if constexpr (PK) {
        const WT* gb = gw + (size_t)(((n * 16 + lm) * 16 + ss * 4 + quad) * 48);
        wg = g8(gb + 16); vg = g8(gb + 40);
      } else {
        const int wr0 = (n * 16 + lm) * H, kk = ss * 32 + quad * 8;
        wg = g8(wihf + wr0 + 256 * H + kk); vg = g8(whhf + wr0 + 256 * H + kk);
      }
      agi = mfma16(ao0[ss], wg, agi);
      agh = mfma16(ah0[ss], vg, agh);
    }
    bf16x8 idn = (n & 1) ? id1 : id0;
    f32x4 hold0 = mfma16(ah0[n >> 1], idn, fz);
    const float big = bih[c + 256], bhg = bhh[c + 256];
#pragma unroll
    for (int r = 0; r < 4; ++r) {
      float ng = tanh_(agi[r] + big + rg[r] * (agh[r] + bhg));
      float hnew = (1.f - zg[r]) * ng + zg[r] * hold0[r];
      if (base + quad * 4 + r < NN) {
        x[(size_t)irow[r] * H + c] = hnew;
        if (ws_ok) atomicAdd(&xsum[brow[r] * H + c], hnew);
      }
    }
  }
}

// ---------------- global model: MLP(2H->H->H) + GRU, 1 block ----------------
template <typename WT, bool PK>
__global__ __launch_bounds__(256) void glob_kernel(
    float* __restrict__ u, const float* __restrict__ xsum, const int* __restrict__ ncnt,
    const WT* __restrict__ w1, const float* __restrict__ b1,
    const WT* __restrict__ w2, const float* __restrict__ b2,
    const WT* __restrict__ gw, const WT* __restrict__ wihf, const WT* __restrict__ whhf,
    const float* __restrict__ bih, const float* __restrict__ bhh,
    float* __restrict__ out, int t, int ws_ok) {
  __shared__ __bf16 lds[4][16 * LROW];
  const int wave = threadIdx.x >> 6, lane = threadIdx.x & 63;
  const int lm = lane & 15, quad = lane >> 4;
  __bf16* myl = lds[wave];
  const int row = wave * 16 + lm;
  const float inv = ws_ok ? 1.f / fmaxf((float)ncnt[row], 1.f) : 1.f;

  f32x4 acc[8] = {};
  bf16x8 ah[4];
#pragma unroll
  for (int seg = 0; seg < 2; ++seg) {
#pragma unroll
    for (int ss = 0; ss < 4; ++ss) {
      const int kk = ss * 32 + quad * 8;
      bf16x8 a;
      if (seg == 0) {
        a = g8(u + (size_t)row * H + kk);
        ah[ss] = a;
      } else if (ws_ok) {
        float4 lo = *(const float4*)(xsum + (size_t)row * H + kk);
        float4 hi = *(const float4*)(xsum + (size_t)row * H + kk + 4);
        a = cvt8s(lo, hi, inv);
      } else a = zero8();
#pragma unroll
      for (int n = 0; n < 8; ++n) {
        bf16x8 bf = g8(w1 + (size_t)(n * 16 + lm) * 256 + seg * 128 + kk);
        acc[n] = mfma16(a, bf, acc[n]);
      }
    }
  }
#pragma unroll
  for (int n = 0; n < 8; ++n) {
    const float bb = b1[n * 16 + lm];
#pragma unroll
    for (int r = 0; r < 4; ++r)
      myl[(quad * 4 + r) * LROW + n * 16 + lm] = (__bf16)fmaxf(acc[n][r] + bb, 0.f);
  }
  LDS_FENCE();
  bf16x8 a2[4];
#pragma unroll
  for (int ss = 0; ss < 4; ++ss) a2[ss] = g8(myl + lm * LROW + ss * 32 + quad * 8);
  f32x4 acc2[8] = {};
#pragma unroll
  for (int ss = 0; ss < 4; ++ss) {
    const int kk = ss * 32 + quad * 8;
#pragma unroll
    for (int n = 0; n < 8; ++n) {
      bf16x8 bf = g8(w2 + (size_t)(n * 16 + lm) * H + kk);
      acc2[n] = mfma16(a2[ss], bf, acc2[n]);
    }
  }
  LDS_FENCE();
#pragma unroll
  for (int n = 0; n < 8; ++n) {
    const float bb = b2[n * 16 + lm];
#pragma unroll
    for (int r = 0; r < 4; ++r)
      myl[(quad * 4 + r) * LROW + n * 16 + lm] = (__bf16)(acc2[n][r] + bb);
  }
  LDS_FENCE();
  bf16x8 ao[4];
#pragma unroll
  for (int ss = 0; ss < 4; ++ss) ao[ss] = g8(myl + lm * LROW + ss * 32 + quad * 8);
  bf16x8 id0, id1;
  make_id(id0, id1, lm, quad);
  const f32x4 fz = {0.f, 0.f, 0.f, 0.f};
  for (int n = 0; n < 8; ++n) {
    f32x4 air = {}, aiz = {}, aig = {}, ahr = {}, ahz = {}, ahg = {};
#pragma unroll
    for (int ss = 0; ss < 4; ++ss) {
      bf16x8 wr, wz, wg, vr, vz, vg;
      if constexpr (PK) {
        const WT* gb = gw + (size_t)(((n * 16 + lm) * 16 + ss * 4 + quad) * 48);
        wr = g8(gb); wz = g8(gb + 8); wg = g8(gb + 16);
        vr = g8(gb + 24); vz = g8(gb + 32); vg = g8(gb + 40);
      } else {
        const int wr0 = (n * 16 + lm) * H, kk = ss * 32 + quad * 8;
        wr = g8(wihf + wr0 + kk); wz = g8(wihf + wr0 + 128 * H + kk); wg = g8(wihf + wr0 + 256 * H + kk);
        vr = g8(whhf + wr0 + kk); vz = g8(whhf + wr0 + 128 * H + kk); vg = g8(whhf + wr0 + 256 * H + kk);
      }
      air = mfma16(ao[ss], wr, air); aiz = mfma16(ao[ss], wz, aiz); aig = mfma16(ao[ss], wg, aig);
      ahr = mfma16(ah[ss], vr, ahr); ahz = mfma16(ah[ss], vz, ahz); ahg = mfma16(ah[ss], vg, ahg);
    }
    bf16x8 idn = (n & 1) ? id1 : id0;
    f32x4 hold = mfma16(ah[n >> 1], idn, fz);
    const int c = n * 16 + lm;
    const float bir = bih[c], biz = bih[c + 128], big = bih[c + 256];
    const float bhr = bhh[c], bhz = bhh[c + 128], bhg = bhh[c + 256];
#pragma unroll
    for (int r = 0; r < 4; ++r) {
      const int rowC = wave * 16 + quad * 4 + r;
      float rg = sigm(air[r] + bir + ahr[r] + bhr);
      float zg = sigm(aiz[r] + biz + ahz[r] + bhz);
      float ng = tanh_(aig[r] + big + rg * (ahg[r] + bhg));
      float hnew = (1.f - zg) * ng + zg * hold[r];
      u[(size_t)rowC * H + c] = hnew;
      out[(size_t)(rowC * NSTEPS + t) * H + c] = hnew;
    }
  }
}

extern "C" void kernel_launch(void* const* d_in, const int* in_sizes, int n_in,
                              void* d_out, int out_size, void* d_ws, size_t ws_size,
                              hipStream_t stream) {
  float* x = (float*)d_in[0];
  const int* ei = (const int*)d_in[1];
  float* ea = (float*)d_in[2];
  float* u = (float*)d_in[3];
  const int* batch = (const int*)d_in[4];
  float* out = (float*)d_out;

  char* ws = (char*)d_ws;
  float* agg = (float*)ws;                                        // NN*H f32
  float* xsum = (float*)(ws + (size_t)NN * H * 4);                // NB*H f32
  int* dcnt = (int*)(ws + (size_t)NN * H * 4 + (size_t)NB * H * 4);
  int* ncnt = dcnt + NN;
  __bf16* wbuf = (__bf16*)(ws + (size_t)NN * H * 4 + (size_t)NB * H * 4 + (size_t)(NN + NB) * 4);
  const size_t need = (size_t)NN * H * 4 + (size_t)NB * H * 4 + (size_t)(NN + NB) * 4 +
                      (size_t)OW_TOTAL * 2;
  const int ws_ok = (ws_size >= need) ? 1 : 0;

  if (ws_ok) {
    W6 w;
    w.p[0] = (const float*)d_in[5];   // ew1
    w.p[1] = (const float*)d_in[7];   // ew2
    w.p[2] = (const float*)d_in[9];   // nw1
    w.p[3] = (const float*)d_in[11];  // nw2
    w.p[4] = (const float*)d_in[13];  // gw1
    w.p[5] = (const float*)d_in[15];  // gw2
    G6 g;
    g.p[0] = (const float*)d_in[17];  // ewih
    g.p[1] = (const float*)d_in[18];  // ewhh
    g.p[2] = (const float*)d_in[21];  // nwih
    g.p[3] = (const float*)d_in[22];  // nwhh
    g.p[4] = (const float*)d_in[25];  // gwih
    g.p[5] = (const float*)d_in[26];  // gwhh
    cvt_kernel<<<(OW_EG / 8 + 255) / 256, 256, 0, stream>>>(w, wbuf);
    gru_pack_kernel<<<(3 * 12288 + 255) / 256, 256, 0, stream>>>(g, wbuf + OW_EG);
    hipMemsetAsync(dcnt, 0, (NN + NB) * sizeof(int), stream);
    count_kernel<<<(NE + 255) / 256, 256, 0, stream>>>(ei + NE, batch, dcnt, ncnt);
  }

  for (int t = 0; t < NSTEPS; ++t) {
    if (ws_ok) {
      hipMemsetAsync(agg, 0, (size_t)NN * H * sizeof(float), stream);
      hipMemsetAsync(xsum, 0, (size_t)NB * H * sizeof(float), stream);
      edge_kernel<__bf16, true><<<(NE + 127) / 128, 256, 0, stream>>>(
          x, ei, ea, u, batch,
          wbuf + OW_EW1, (const float*)d_in[6], wbuf + OW_EW2, (const float*)d_in[8],
          wbuf + OW_EG, wbuf + OW_EG, wbuf + OW_EG,
          (const float*)d_in[19], (const float*)d_in[20], agg, 1);
      node_kernel<__bf16, true><<<(NN + 63) / 64, 256, 0, stream>>>(
          x, u, batch, agg, dcnt,
          wbuf + OW_NW1, (const float*)d_in[10], wbuf + OW_NW2, (const float*)d_in[12],
          wbuf + OW_NG, wbuf + OW_NG, wbuf + OW_NG,
          (const float*)d_in[23], (const float*)d_in[24], xsum, 1);
      glob_kernel<__bf16, true><<<1, 256, 0, stream>>>(
          u, xsum, ncnt,
          wbuf + OW_GW1, (const float*)d_in[14], wbuf + OW_GW2, (const float*)d_in[16],
          wbuf + OW_GG, wbuf + OW_GG, wbuf + OW_GG,
          (const float*)d_in[27], (const float*)d_in[28], out, t, 1);
    } else {
      // never-taken safety path: raw f32 weights, no aggregation workspace
      edge_kernel<float, false><<<(NE + 127) / 128, 256, 0, stream>>>(
          x, ei, ea, u, batch,
          (const float*)d_in[5], (const float*)d_in[6], (const float*)d_in[7], (const float*)d_in[8],
          (const float*)d_in[17], (const float*)d_in[17], (const float*)d_in[18],
          (const float*)d_in[19], (const float*)d_in[20], agg, 0);
      node_kernel<float, false><<<(NN + 63) / 64, 256, 0, stream>>>(
          x, u, batch, agg, dcnt,
          (const float*)d_in[9], (const float*)d_in[10], (const float*)d_in[11], (const float*)d_in[12],
          (const float*)d_in[21], (const float*)d_in[21], (const float*)d_in[22],
          (const float*)d_in[23], (const float*)d_in[24], xsum, 0);
      glob_kernel<float, false><<<1, 256, 0, stream>>>(
          u, xsum, ncnt,
          (const float*)d_in[13], (const float*)d_in[14], (const float*)d_in[15], (const float*)d_in[16],
          (const float*)d_in[25], (const float*)d_in[25], (const float*)d_in[26],
          (const float*)d_in[27], (const float*)d_in[28], out, t, 0);
    }
  }
}